// Round 1
// baseline (450.328 us; speedup 1.0000x reference)
//
#include <hip/hip_runtime.h>
#include <hip/hip_bf16.h>

#define B_  8
#define N_  131072
#define C_  64
#define SD_ 256

typedef __attribute__((ext_vector_type(8))) short  short8;   // 8 bf16 (4 VGPRs)
typedef __attribute__((ext_vector_type(4))) float  floatx4;  // MFMA C/D frag

static __device__ inline short bf16_of(float f) {
    __hip_bfloat16 h = __float2bfloat16(f);
    return *reinterpret_cast<short*>(&h);
}

// ---------------------------------------------------------------------------
// Kernel 1: per-batch modulated + demodulated weight -> bf16, layout (b, o, i)
// One block per batch, 256 threads. Tiny (runs in a few microseconds).
// ---------------------------------------------------------------------------
__global__ void modw_kernel(const float* __restrict__ style,
                            const float* __restrict__ weight,
                            const float* __restrict__ mod_weight,
                            const float* __restrict__ mod_bias,
                            __hip_bfloat16* __restrict__ wout) {
    const int b = blockIdx.x;
    const int t = threadIdx.x;          // 256
    __shared__ float part[4][64];
    __shared__ float s_sh[64];

    // s[i] = (1/sqrt(256)) * sum_d style[b][d]*mod_weight[i][d] + mod_bias[i] + 1
    const int i   = t & 63;
    const int seg = t >> 6;             // 4 segments of 64 d-values
    {
        const float* st = style + b * SD_ + seg * 64;
        const float* mw = mod_weight + i * SD_ + seg * 64;
        float p = 0.f;
        #pragma unroll
        for (int d = 0; d < 64; ++d) p += st[d] * mw[d];
        part[seg][i] = p;
    }
    __syncthreads();
    if (t < 64) {
        float s = (part[0][t] + part[1][t] + part[2][t] + part[3][t]) * 0.0625f
                  + mod_bias[t] + 1.0f;
        s_sh[t] = s;
    }
    __syncthreads();
    if (t < 64) {
        const int o = t;
        float wt[64];
        float sumsq = 0.f;
        #pragma unroll
        for (int ii = 0; ii < 64; ++ii) {
            float v = 0.125f * weight[o * 64 + ii] * s_sh[ii];  // scale=1/sqrt(64)
            wt[ii] = v;
            sumsq += v * v;
        }
        const float demod = rsqrtf(sumsq + 1e-8f);
        #pragma unroll
        for (int ii = 0; ii < 64; ++ii)
            wout[(b * 64 + o) * 64 + ii] = __float2bfloat16(wt[ii] * demod);
    }
}

// ---------------------------------------------------------------------------
// Kernel 2: out[b] = x[b] @ w[b]^T + bias, streamed via bf16 MFMA.
// One wave = 64 points (4 MFMA point-tiles of 16), all 64 outputs.
// 4096 blocks x 256 threads = 16384 waves; 2048 waves per batch.
// ---------------------------------------------------------------------------
__global__ __launch_bounds__(256) void conv_kernel(
        const float* __restrict__ x,
        const __hip_bfloat16* __restrict__ wmod,
        const float* __restrict__ bias,
        float* __restrict__ out) {
    const int lane = threadIdx.x & 63;
    const int wid  = threadIdx.x >> 6;
    const int gw   = blockIdx.x * 4 + wid;   // 0..16383
    const int b    = gw >> 11;               // 2048 waves / batch
    const int p0   = (gw & 2047) * 64;       // first point of this wave
    const int row  = lane & 15;              // A.m / B.n / D.col index
    const int quad = lane >> 4;              // k-quad / D.row-quad

    // --- B fragments: w[o=nt*16+row][k=ks*32+quad*8 ..+8], bf16, L2-resident
    short8 bf[4][2];
    const short* wb = (const short*)(wmod) + b * 64 * 64;
    #pragma unroll
    for (int nt = 0; nt < 4; ++nt)
        #pragma unroll
        for (int ks = 0; ks < 2; ++ks)
            bf[nt][ks] = *(const short8*)(wb + (nt * 16 + row) * 64 + ks * 32 + quad * 8);

    // --- bias (zeros in this problem, but reference adds it): D.col = row
    float bias_v[4];
    #pragma unroll
    for (int nt = 0; nt < 4; ++nt) bias_v[nt] = bias[nt * 16 + row];

    const size_t base = ((size_t)b * N_ + p0) * C_;
    const float* xb = x + base;
    float*       ob = out + base;

    #pragma unroll
    for (int pt = 0; pt < 4; ++pt) {
        // A fragments: x[p=pt*16+row][k], k = quad*8..+8 (frag0), +32 (frag1)
        const float* xr = xb + (pt * 16 + row) * C_ + quad * 8;
        floatx4 a0 = *(const floatx4*)(xr);
        floatx4 a1 = *(const floatx4*)(xr + 4);
        floatx4 a2 = *(const floatx4*)(xr + 32);
        floatx4 a3 = *(const floatx4*)(xr + 36);

        short8 af0, af1;
        #pragma unroll
        for (int j = 0; j < 4; ++j) {
            af0[j]     = bf16_of(a0[j]);
            af0[j + 4] = bf16_of(a1[j]);
            af1[j]     = bf16_of(a2[j]);
            af1[j + 4] = bf16_of(a3[j]);
        }

        floatx4 acc[4];
        #pragma unroll
        for (int nt = 0; nt < 4; ++nt) {
            acc[nt] = (floatx4){bias_v[nt], bias_v[nt], bias_v[nt], bias_v[nt]};
            acc[nt] = __builtin_amdgcn_mfma_f32_16x16x32_bf16(af0, bf[nt][0], acc[nt], 0, 0, 0);
            acc[nt] = __builtin_amdgcn_mfma_f32_16x16x32_bf16(af1, bf[nt][1], acc[nt], 0, 0, 0);
        }

        // D[m][n]: m = quad*4 + r (point), n = nt*16 + row (output channel)
        #pragma unroll
        for (int nt = 0; nt < 4; ++nt)
            #pragma unroll
            for (int r = 0; r < 4; ++r)
                ob[(pt * 16 + quad * 4 + r) * C_ + nt * 16 + row] = acc[nt][r];
    }
}

extern "C" void kernel_launch(void* const* d_in, const int* in_sizes, int n_in,
                              void* d_out, int out_size, void* d_ws, size_t ws_size,
                              hipStream_t stream) {
    const float* x          = (const float*)d_in[0];
    const float* style      = (const float*)d_in[1];
    const float* weight     = (const float*)d_in[2];
    const float* bias       = (const float*)d_in[3];
    const float* mod_weight = (const float*)d_in[4];
    const float* mod_bias   = (const float*)d_in[5];
    float* out = (float*)d_out;
    __hip_bfloat16* wmod = (__hip_bfloat16*)d_ws;   // 8*64*64*2 = 64 KB

    modw_kernel<<<dim3(B_), dim3(256), 0, stream>>>(style, weight, mod_weight, mod_bias, wmod);
    conv_kernel<<<dim3((B_ * N_) / 256), dim3(256), 0, stream>>>(x, wmod, bias, out);
}